// Round 1
// baseline (35.004 us; speedup 1.0000x reference)
//
#include <hip/hip_runtime.h>

// LabPool: out[d,l] = max_n( labmap[l,n] * X[d,n] )  for labmap one-hot over l.
// Since each label group is a strict subset of items, zeros are always in the
// max, so out[d,l] = max over group members of fmax(X[d,n], 0) with identity 0.
// All results >= 0 -> uint bit-pattern ordering == float ordering.

constexpr int L = 32;
constexpr int D = 64;
constexpr int TI = 400;          // items per block (200000 / 400 = 500 blocks)
constexpr int SLOTS = D * L;     // 2048

__global__ __launch_bounds__(256)
void labpool_partial(const float* __restrict__ labmap,
                     const float* __restrict__ X,
                     unsigned* __restrict__ ws,     // [gridDim.x][SLOTS] partials, or null
                     unsigned* __restrict__ gout,   // fallback: global atomic target
                     int N)
{
    __shared__ unsigned sm[SLOTS];          // 8 KB partial max table (uint-punned floats)
    __shared__ unsigned char lab[TI];       // per-item label for this tile
    const int tid = threadIdx.x;
    const int n0 = blockIdx.x * TI;

    for (int i = tid; i < SLOTS; i += 256) sm[i] = 0u;

    constexpr int V = TI / 4;               // 100 float4 per row-tile
    // Phase 1: decode labels from one-hot labmap rows (coalesced float4 reads).
    for (int idx = tid; idx < L * V; idx += 256) {
        const int l = idx / V;
        const int v = idx - l * V;
        const float4 m = *reinterpret_cast<const float4*>(labmap + (size_t)l * N + n0 + 4 * v);
        if (m.x > 0.5f) lab[4 * v + 0] = (unsigned char)l;
        if (m.y > 0.5f) lab[4 * v + 1] = (unsigned char)l;
        if (m.z > 0.5f) lab[4 * v + 2] = (unsigned char)l;
        if (m.w > 0.5f) lab[4 * v + 3] = (unsigned char)l;
    }
    __syncthreads();

    // Phase 2: stream X tile, LDS atomicMax into per-block table.
    for (int idx = tid; idx < D * V; idx += 256) {
        const int d = idx / V;
        const int v = idx - d * V;
        const float4 x = *reinterpret_cast<const float4*>(X + (size_t)d * N + n0 + 4 * v);
        const uchar4 lv = *reinterpret_cast<const uchar4*>(&lab[4 * v]);
        atomicMax(&sm[d * L + lv.x], __float_as_uint(fmaxf(x.x, 0.0f)));
        atomicMax(&sm[d * L + lv.y], __float_as_uint(fmaxf(x.y, 0.0f)));
        atomicMax(&sm[d * L + lv.z], __float_as_uint(fmaxf(x.z, 0.0f)));
        atomicMax(&sm[d * L + lv.w], __float_as_uint(fmaxf(x.w, 0.0f)));
    }
    __syncthreads();

    if (ws) {
        unsigned* dst = ws + (size_t)blockIdx.x * SLOTS;
        for (int i = tid; i < SLOTS; i += 256) dst[i] = sm[i];
    } else {
        for (int i = tid; i < SLOTS; i += 256) atomicMax(&gout[i], sm[i]);
    }
}

__global__ __launch_bounds__(256)
void labpool_reduce(const unsigned* __restrict__ ws, float* __restrict__ out, int nb)
{
    __shared__ unsigned red[8][32];
    const int tid = threadIdx.x;
    const int bq = tid >> 5;       // 0..7
    const int sl = tid & 31;       // 0..31
    const int s0 = blockIdx.x * 32;
    unsigned m = 0u;
    for (int b = bq; b < nb; b += 8) {
        const unsigned v = ws[(size_t)b * SLOTS + s0 + sl];
        m = (v > m) ? v : m;
    }
    red[bq][sl] = m;
    __syncthreads();
    if (bq == 0) {
        unsigned r = red[0][sl];
#pragma unroll
        for (int q = 1; q < 8; ++q) {
            const unsigned v = red[q][sl];
            r = (v > r) ? v : r;
        }
        out[s0 + sl] = __uint_as_float(r);
    }
}

__global__ void zero_out_k(unsigned* p, int n)
{
    const int i = blockIdx.x * 256 + threadIdx.x;
    if (i < n) p[i] = 0u;
}

extern "C" void kernel_launch(void* const* d_in, const int* in_sizes, int n_in,
                              void* d_out, int out_size, void* d_ws, size_t ws_size,
                              hipStream_t stream)
{
    const float* labmap = (const float*)d_in[0];   // [L, N]
    const float* X      = (const float*)d_in[1];   // [D, N]
    const int N = in_sizes[0] / L;                 // 200000
    const int nb = N / TI;                         // 500

    const size_t need = (size_t)nb * SLOTS * sizeof(unsigned);
    if (d_ws && ws_size >= need) {
        unsigned* ws = (unsigned*)d_ws;
        labpool_partial<<<nb, 256, 0, stream>>>(labmap, X, ws, nullptr, N);
        labpool_reduce<<<SLOTS / 32, 256, 0, stream>>>(ws, (float*)d_out, nb);
    } else {
        unsigned* gout = (unsigned*)d_out;
        zero_out_k<<<(SLOTS + 255) / 256, 256, 0, stream>>>(gout, SLOTS);
        labpool_partial<<<nb, 256, 0, stream>>>(labmap, X, nullptr, gout, N);
    }
}